// Round 2
// baseline (1025.470 us; speedup 1.0000x reference)
//
#include <hip/hip_runtime.h>
#include <hip/hip_bf16.h>
#include <stdint.h>

// ---------------------------------------------------------------------------
// RWKV self-attention: per-stage mix -> GEMM (bf16 MFMA) x3 -> WKV -> out GEMM
// B=4, T=2048, H=2048. GEMM = verified m97 structure (128x128 tile, BK=32,
// 16x16x32 bf16 MFMA, global_load_lds width=16).
// Workspace budget: WT 8.4MB + x 33.5MB + k/v/r(fp16) 100.7MB = 142.6 MB.
// ---------------------------------------------------------------------------

typedef short short8 __attribute__((ext_vector_type(8)));   // 8 bf16 (4 VGPRs)
typedef float f32x4 __attribute__((ext_vector_type(4)));

__device__ __forceinline__ void gld_lds16(const void* gptr, void* lptr) {
  void* g = const_cast<void*>(gptr);
  __builtin_amdgcn_global_load_lds(
      (__attribute__((address_space(1))) void*)g,
      (__attribute__((address_space(3))) void*)lptr, 16, 0, 0);
}

__device__ __forceinline__ unsigned short f2bf(float f) {
  __bf16 b = (__bf16)f;
  return __builtin_bit_cast(unsigned short, b);
}
__device__ __forceinline__ unsigned short f2h(float f) {
  _Float16 h = (_Float16)f;
  return __builtin_bit_cast(unsigned short, h);
}
__device__ __forceinline__ float h2f(unsigned short u) {
  return (float)__builtin_bit_cast(_Float16, u);
}

// ---------------- weight transpose + fp32->bf16 cast -----------------------
// WT[n][k] = (bf16) W[k][n]
__global__ void transpose_cast(const float* __restrict__ W,
                               unsigned short* __restrict__ WT, int n) {
  __shared__ float tile[32][33];
  const int tx = threadIdx.x, ty = threadIdx.y;
  const int x = blockIdx.x * 32 + tx;
#pragma unroll
  for (int j = 0; j < 32; j += 8) {
    int row = blockIdx.y * 32 + ty + j;
    tile[ty + j][tx] = W[(size_t)row * n + x];
  }
  __syncthreads();
#pragma unroll
  for (int j = 0; j < 32; j += 8) {
    int orow = blockIdx.x * 32 + ty + j;  // n index
    int ocol = blockIdx.y * 32 + tx;      // k index
    WT[(size_t)orow * n + ocol] = f2bf(tile[tx][ty + j]);
  }
}

// ---------------- time-shift mix (fp32 in, bf16 out), one mix vector -------
__global__ void mix_kernel(const float4* __restrict__ hid,
                           const float4* __restrict__ m4,
                           ushort4* __restrict__ x, int T, int H4) {
  size_t idx = (size_t)blockIdx.x * blockDim.x + threadIdx.x;
  int c4 = (int)(idx % H4);
  int t = (int)(idx / H4) % T;
  float4 h = hid[idx];
  float4 p = make_float4(0.f, 0.f, 0.f, 0.f);
  if (t != 0) p = hid[idx - H4];
  float4 m = m4[c4];
  ushort4 o;
  o.x = f2bf(h.x * m.x + p.x * (1.f - m.x));
  o.y = f2bf(h.y * m.y + p.y * (1.f - m.y));
  o.z = f2bf(h.z * m.z + p.z * (1.f - m.z));
  o.w = f2bf(h.w * m.w + p.w * (1.f - m.w));
  x[idx] = o;
}

// ---------------- bf16 MFMA GEMM: C[MxN] = A[MxK] * Bt[NxK]^T --------------
#define MODE_F32 0
#define MODE_F16 1
#define MODE_F16_SIG 2

__global__ __launch_bounds__(256) void gemm_bt(
    const unsigned short* __restrict__ A, const unsigned short* __restrict__ Bt,
    void* __restrict__ Cv, int N, int K, int mode) {
  __shared__ unsigned short lta[128 * 32];
  __shared__ unsigned short ltb[128 * 32];

  const int tid = threadIdx.x;
  const int lane = tid & 63;
  const int wave = tid >> 6;
  const int wm = wave >> 1, wn = wave & 1;
  const int quad = lane >> 4, lm = lane & 15;

  const int mBase = blockIdx.y * 128;
  const int nBase = blockIdx.x * 128;

  // staging: 512 chunks of 16B (8 bf16) per tile; chunk c -> row c>>2,
  // kcol (c&3)*8; LDS elem offset 8*c -> per-lane addr == wave base+lane*16.
  const int ca0 = tid, ca1 = tid + 256;
  const unsigned short* Ag0 = A + (size_t)(mBase + (ca0 >> 2)) * K + (ca0 & 3) * 8;
  const unsigned short* Ag1 = A + (size_t)(mBase + (ca1 >> 2)) * K + (ca1 & 3) * 8;
  const unsigned short* Bg0 = Bt + (size_t)(nBase + (ca0 >> 2)) * K + (ca0 & 3) * 8;
  const unsigned short* Bg1 = Bt + (size_t)(nBase + (ca1 >> 2)) * K + (ca1 & 3) * 8;
  unsigned short* La0 = lta + ca0 * 8;
  unsigned short* La1 = lta + ca1 * 8;
  unsigned short* Lb0 = ltb + ca0 * 8;
  unsigned short* Lb1 = ltb + ca1 * 8;

  // fragment LDS pointers: A[m=lm][k=quad*8+j]
  const unsigned short* lap[4];
  const unsigned short* lbp[4];
#pragma unroll
  for (int i = 0; i < 4; ++i) {
    lap[i] = lta + (wm * 64 + i * 16 + lm) * 32 + quad * 8;
    lbp[i] = ltb + (wn * 64 + i * 16 + lm) * 32 + quad * 8;
  }

  f32x4 acc[4][4];
#pragma unroll
  for (int i = 0; i < 4; ++i)
#pragma unroll
    for (int j = 0; j < 4; ++j) {
      f32x4 zz = {0.f, 0.f, 0.f, 0.f};
      acc[i][j] = zz;
    }

  for (int k0 = 0; k0 < K; k0 += 32) {
    __syncthreads();
    gld_lds16(Ag0 + k0, La0);
    gld_lds16(Ag1 + k0, La1);
    gld_lds16(Bg0 + k0, Lb0);
    gld_lds16(Bg1 + k0, Lb1);
    __syncthreads();
    short8 aF[4], bF[4];
#pragma unroll
    for (int i = 0; i < 4; ++i) aF[i] = *(const short8*)lap[i];
#pragma unroll
    for (int j = 0; j < 4; ++j) bF[j] = *(const short8*)lbp[j];
#pragma unroll
    for (int i = 0; i < 4; ++i)
#pragma unroll
      for (int j = 0; j < 4; ++j)
        acc[i][j] = __builtin_amdgcn_mfma_f32_16x16x32_bf16(aF[i], bF[j],
                                                            acc[i][j], 0, 0, 0);
  }

  // epilogue: C/D layout col=lane&15, row=quad*4+reg  [m89/m91 verified]
#pragma unroll
  for (int i = 0; i < 4; ++i) {
#pragma unroll
    for (int j = 0; j < 4; ++j) {
      const int r0 = mBase + wm * 64 + i * 16 + quad * 4;
      const int cc = nBase + wn * 64 + j * 16 + lm;
#pragma unroll
      for (int rg = 0; rg < 4; ++rg) {
        float x = acc[i][j][rg];
        size_t off = (size_t)(r0 + rg) * N + cc;
        if (mode == MODE_F32) {
          ((float*)Cv)[off] = x;
        } else {
          if (mode == MODE_F16_SIG) x = 1.0f / (1.0f + __expf(-x));
          ((unsigned short*)Cv)[off] = f2h(x);
        }
      }
    }
  }
}

// ---------------- WKV recurrence (fp32 compute, fp16-in, bf16-out) ---------
// y aliases rr (in-place, read-before-write per element per thread).
__global__ void wkv_kernel(const unsigned short* kk, const unsigned short* vv,
                           const unsigned short* rr,
                           const float* __restrict__ tdec,
                           const float* __restrict__ tfir, unsigned short* y,
                           int T, int H) {
  int ch = blockIdx.x * blockDim.x + threadIdx.x;  // [0, B*H)
  int b = ch / H;
  int h = ch - b * H;
  const float td = -__expf(tdec[h]);
  const float tf = tfir[h];
  size_t base = (size_t)b * T * H + h;
  const unsigned short* kp = kk + base;
  const unsigned short* vp = vv + base;
  const unsigned short* rp = rr + base;
  unsigned short* yp = y + base;

  float num = 0.f, den = 0.f, mx = -1e38f;
  constexpr int UF = 16;
  unsigned short kb[UF], vb[UF], rb[UF];
#pragma unroll
  for (int u = 0; u < UF; ++u) {  // prefetch block 0
    size_t o = (size_t)u * H;
    kb[u] = kp[o];
    vb[u] = vp[o];
    rb[u] = rp[o];
  }
  for (int t0 = 0; t0 < T; t0 += UF) {
    unsigned short kn[UF], vn[UF], rn[UF];
    if (t0 + UF < T) {  // prefetch next block while computing this one
#pragma unroll
      for (int u = 0; u < UF; ++u) {
        size_t o = (size_t)(t0 + UF + u) * H;
        kn[u] = kp[o];
        vn[u] = vp[o];
        rn[u] = rp[o];
      }
    }
    unsigned short oc[UF];
#pragma unroll
    for (int u = 0; u < UF; ++u) {
      float kt = h2f(kb[u]), vt = h2f(vb[u]);
      float ktf = kt + tf;
      float mfo = fmaxf(mx, ktf);
      float e1 = __expf(mx - mfo);
      float e2 = __expf(ktf - mfo);
      float out = __fdividef(e1 * num + e2 * vt, e1 * den + e2);
      float mtd = mx + td;
      float mfs = fmaxf(mtd, kt);
      float e1s = __expf(mtd - mfs);
      float e2s = __expf(kt - mfs);
      num = e1s * num + e2s * vt;
      den = e1s * den + e2s;
      mx = mfs;
      oc[u] = f2bf(h2f(rb[u]) * out);
    }
#pragma unroll
    for (int u = 0; u < UF; ++u) yp[(size_t)(t0 + u) * H] = oc[u];
#pragma unroll
    for (int u = 0; u < UF; ++u) {
      kb[u] = kn[u];
      vb[u] = vn[u];
      rb[u] = rn[u];
    }
  }
}

// ---------------------------------------------------------------------------
extern "C" void kernel_launch(void* const* d_in, const int* in_sizes, int n_in,
                              void* d_out, int out_size, void* d_ws,
                              size_t ws_size, hipStream_t stream) {
  const int Bb = 4, T = 2048, H = 2048;
  const int M = Bb * T;  // 8192

  const float* hidden = (const float*)d_in[0];
  const float* time_decay = (const float*)d_in[1];
  const float* time_first = (const float*)d_in[2];
  const float* tmk = (const float*)d_in[3];
  const float* tmv = (const float*)d_in[4];
  const float* tmr = (const float*)d_in[5];
  const float* Wk = (const float*)d_in[6];
  const float* Wv = (const float*)d_in[7];
  const float* Wr = (const float*)d_in[8];
  const float* Wo = (const float*)d_in[9];
  float* out = (float*)d_out;

  const size_t szWT = (size_t)H * H * 2;   // 8.4 MB  (bf16, reused x4)
  const size_t szMH = (size_t)M * H * 2;   // 33.5 MB (bf16/fp16 M x H)
  const size_t need = szWT + 4 * szMH + 1024;
  if (ws_size < need) return;  // diagnostic guard: clean absmax fail, no fault

  char* ws = (char*)d_ws;
  size_t off = 0;
  auto alloc = [&](size_t bytes) {
    char* p = ws + off;
    off += (bytes + 255) & ~(size_t)255;
    return p;
  };
  unsigned short* WT = (unsigned short*)alloc(szWT);
  unsigned short* xbuf = (unsigned short*)alloc(szMH);  // mix out, reused x3
  unsigned short* kbuf = (unsigned short*)alloc(szMH);  // fp16
  unsigned short* vbuf = (unsigned short*)alloc(szMH);  // fp16
  unsigned short* rbuf = (unsigned short*)alloc(szMH);  // fp16; y (bf16) in-place

  const dim3 txG(H / 32, H / 32), txB(32, 8);
  const int H4 = H / 4;
  const dim3 mixG((M * H4) / 256), mixB(256);
  const dim3 gmG(H / 128, M / 128), gmB(256);

  // k path
  transpose_cast<<<txG, txB, 0, stream>>>(Wk, WT, H);
  mix_kernel<<<mixG, mixB, 0, stream>>>((const float4*)hidden,
                                        (const float4*)tmk, (ushort4*)xbuf, T, H4);
  gemm_bt<<<gmG, gmB, 0, stream>>>(xbuf, WT, kbuf, H, H, MODE_F16);
  // v path
  transpose_cast<<<txG, txB, 0, stream>>>(Wv, WT, H);
  mix_kernel<<<mixG, mixB, 0, stream>>>((const float4*)hidden,
                                        (const float4*)tmv, (ushort4*)xbuf, T, H4);
  gemm_bt<<<gmG, gmB, 0, stream>>>(xbuf, WT, vbuf, H, H, MODE_F16);
  // r path (sigmoid fused)
  transpose_cast<<<txG, txB, 0, stream>>>(Wr, WT, H);
  mix_kernel<<<mixG, mixB, 0, stream>>>((const float4*)hidden,
                                        (const float4*)tmr, (ushort4*)xbuf, T, H4);
  gemm_bt<<<gmG, gmB, 0, stream>>>(xbuf, WT, rbuf, H, H, MODE_F16_SIG);

  // WKV scan; y (bf16) overwrites rbuf in place
  wkv_kernel<<<dim3((Bb * H) / 64), dim3(64), 0, stream>>>(
      kbuf, vbuf, rbuf, time_decay, time_first, rbuf, T, H);

  // output GEMM: out = y @ Wo (fp32 out)
  transpose_cast<<<txG, txB, 0, stream>>>(Wo, WT, H);
  gemm_bt<<<gmG, gmB, 0, stream>>>(rbuf, WT, out, H, H, MODE_F32);
}

// Round 3
// 735.224 us; speedup vs baseline: 1.3948x; 1.3948x over previous
//
#include <hip/hip_runtime.h>
#include <hip/hip_bf16.h>
#include <stdint.h>

// ---------------------------------------------------------------------------
// RWKV self-attention: per-stage mix -> GEMM (bf16 MFMA) x3 -> WKV -> out GEMM
// B=4, T=2048, H=2048. GEMM = verified m97 structure (128x128 tile, BK=32,
// 16x16x32 bf16 MFMA, global_load_lds width=16).
// WKV: 3-pass chunked parallel scan (C=32 chunks of L=64) — the recurrence is
// an associative stabilized affine map, so chunk summaries compose exactly.
// Workspace budget: WT 8.4MB + x 33.5MB + k/v/r(fp16) 100.7MB = 142.6 MB.
// (chunk-scan arrays, 6 MB, reuse xbuf which is dead by WKV time)
// ---------------------------------------------------------------------------

typedef short short8 __attribute__((ext_vector_type(8)));   // 8 bf16 (4 VGPRs)
typedef float f32x4 __attribute__((ext_vector_type(4)));

#define WKV_C 32  // chunks per sequence (L = T/WKV_C = 64)

__device__ __forceinline__ void gld_lds16(const void* gptr, void* lptr) {
  void* g = const_cast<void*>(gptr);
  __builtin_amdgcn_global_load_lds(
      (__attribute__((address_space(1))) void*)g,
      (__attribute__((address_space(3))) void*)lptr, 16, 0, 0);
}

__device__ __forceinline__ unsigned short f2bf(float f) {
  __bf16 b = (__bf16)f;
  return __builtin_bit_cast(unsigned short, b);
}
__device__ __forceinline__ unsigned short f2h(float f) {
  _Float16 h = (_Float16)f;
  return __builtin_bit_cast(unsigned short, h);
}
__device__ __forceinline__ float h2f(unsigned short u) {
  return (float)__builtin_bit_cast(_Float16, u);
}

// ---------------- weight transpose + fp32->bf16 cast -----------------------
// WT[n][k] = (bf16) W[k][n]
__global__ void transpose_cast(const float* __restrict__ W,
                               unsigned short* __restrict__ WT, int n) {
  __shared__ float tile[32][33];
  const int tx = threadIdx.x, ty = threadIdx.y;
  const int x = blockIdx.x * 32 + tx;
#pragma unroll
  for (int j = 0; j < 32; j += 8) {
    int row = blockIdx.y * 32 + ty + j;
    tile[ty + j][tx] = W[(size_t)row * n + x];
  }
  __syncthreads();
#pragma unroll
  for (int j = 0; j < 32; j += 8) {
    int orow = blockIdx.x * 32 + ty + j;  // n index
    int ocol = blockIdx.y * 32 + tx;      // k index
    WT[(size_t)orow * n + ocol] = f2bf(tile[tx][ty + j]);
  }
}

// ---------------- time-shift mix (fp32 in, bf16 out), one mix vector -------
__global__ void mix_kernel(const float4* __restrict__ hid,
                           const float4* __restrict__ m4,
                           ushort4* __restrict__ x, int T, int H4) {
  size_t idx = (size_t)blockIdx.x * blockDim.x + threadIdx.x;
  int c4 = (int)(idx % H4);
  int t = (int)(idx / H4) % T;
  float4 h = hid[idx];
  float4 p = make_float4(0.f, 0.f, 0.f, 0.f);
  if (t != 0) p = hid[idx - H4];
  float4 m = m4[c4];
  ushort4 o;
  o.x = f2bf(h.x * m.x + p.x * (1.f - m.x));
  o.y = f2bf(h.y * m.y + p.y * (1.f - m.y));
  o.z = f2bf(h.z * m.z + p.z * (1.f - m.z));
  o.w = f2bf(h.w * m.w + p.w * (1.f - m.w));
  x[idx] = o;
}

// ---------------- bf16 MFMA GEMM: C[MxN] = A[MxK] * Bt[NxK]^T --------------
#define MODE_F32 0
#define MODE_F16 1
#define MODE_F16_SIG 2

__global__ __launch_bounds__(256) void gemm_bt(
    const unsigned short* __restrict__ A, const unsigned short* __restrict__ Bt,
    void* __restrict__ Cv, int N, int K, int mode) {
  __shared__ unsigned short lta[128 * 32];
  __shared__ unsigned short ltb[128 * 32];

  const int tid = threadIdx.x;
  const int lane = tid & 63;
  const int wave = tid >> 6;
  const int wm = wave >> 1, wn = wave & 1;
  const int quad = lane >> 4, lm = lane & 15;

  const int mBase = blockIdx.y * 128;
  const int nBase = blockIdx.x * 128;

  // staging: 512 chunks of 16B (8 bf16) per tile; chunk c -> row c>>2,
  // kcol (c&3)*8; LDS elem offset 8*c -> per-lane addr == wave base+lane*16.
  const int ca0 = tid, ca1 = tid + 256;
  const unsigned short* Ag0 = A + (size_t)(mBase + (ca0 >> 2)) * K + (ca0 & 3) * 8;
  const unsigned short* Ag1 = A + (size_t)(mBase + (ca1 >> 2)) * K + (ca1 & 3) * 8;
  const unsigned short* Bg0 = Bt + (size_t)(nBase + (ca0 >> 2)) * K + (ca0 & 3) * 8;
  const unsigned short* Bg1 = Bt + (size_t)(nBase + (ca1 >> 2)) * K + (ca1 & 3) * 8;
  unsigned short* La0 = lta + ca0 * 8;
  unsigned short* La1 = lta + ca1 * 8;
  unsigned short* Lb0 = ltb + ca0 * 8;
  unsigned short* Lb1 = ltb + ca1 * 8;

  // fragment LDS pointers: A[m=lm][k=quad*8+j]
  const unsigned short* lap[4];
  const unsigned short* lbp[4];
#pragma unroll
  for (int i = 0; i < 4; ++i) {
    lap[i] = lta + (wm * 64 + i * 16 + lm) * 32 + quad * 8;
    lbp[i] = ltb + (wn * 64 + i * 16 + lm) * 32 + quad * 8;
  }

  f32x4 acc[4][4];
#pragma unroll
  for (int i = 0; i < 4; ++i)
#pragma unroll
    for (int j = 0; j < 4; ++j) {
      f32x4 zz = {0.f, 0.f, 0.f, 0.f};
      acc[i][j] = zz;
    }

  for (int k0 = 0; k0 < K; k0 += 32) {
    __syncthreads();
    gld_lds16(Ag0 + k0, La0);
    gld_lds16(Ag1 + k0, La1);
    gld_lds16(Bg0 + k0, Lb0);
    gld_lds16(Bg1 + k0, Lb1);
    __syncthreads();
    short8 aF[4], bF[4];
#pragma unroll
    for (int i = 0; i < 4; ++i) aF[i] = *(const short8*)lap[i];
#pragma unroll
    for (int j = 0; j < 4; ++j) bF[j] = *(const short8*)lbp[j];
#pragma unroll
    for (int i = 0; i < 4; ++i)
#pragma unroll
      for (int j = 0; j < 4; ++j)
        acc[i][j] = __builtin_amdgcn_mfma_f32_16x16x32_bf16(aF[i], bF[j],
                                                            acc[i][j], 0, 0, 0);
  }

  // epilogue: C/D layout col=lane&15, row=quad*4+reg  [m89/m91 verified]
#pragma unroll
  for (int i = 0; i < 4; ++i) {
#pragma unroll
    for (int j = 0; j < 4; ++j) {
      const int r0 = mBase + wm * 64 + i * 16 + quad * 4;
      const int cc = nBase + wn * 64 + j * 16 + lm;
#pragma unroll
      for (int rg = 0; rg < 4; ++rg) {
        float x = acc[i][j][rg];
        size_t off = (size_t)(r0 + rg) * N + cc;
        if (mode == MODE_F32) {
          ((float*)Cv)[off] = x;
        } else {
          if (mode == MODE_F16_SIG) x = 1.0f / (1.0f + __expf(-x));
          ((unsigned short*)Cv)[off] = f2h(x);
        }
      }
    }
  }
}

// ---------------- WKV pass 1: per-chunk summary from zero state ------------
// idx -> (b, c, h); consecutive threads = consecutive h (coalesced).
__global__ void wkv_pass1(const unsigned short* __restrict__ kk,
                          const unsigned short* __restrict__ vv,
                          const float* __restrict__ tdec,
                          float* __restrict__ pn, float* __restrict__ pd,
                          float* __restrict__ pm, int T, int H, int L) {
  int idx = blockIdx.x * blockDim.x + threadIdx.x;  // [0, B*C*H)
  int h = idx % H;
  int bc = idx / H;
  int c = bc % WKV_C;
  int b = bc / WKV_C;
  const float td = -__expf(tdec[h]);
  size_t base = ((size_t)b * T + (size_t)c * L) * H + h;
  const unsigned short* kp = kk + base;
  const unsigned short* vp = vv + base;
  float num = 0.f, den = 0.f, mx = -1e38f;
#pragma unroll 8
  for (int t = 0; t < L; ++t) {
    float kt = h2f(kp[(size_t)t * H]);
    float vt = h2f(vp[(size_t)t * H]);
    float mtd = mx + td;
    float mfs = fmaxf(mtd, kt);
    float e1s = __expf(mtd - mfs);
    float e2s = __expf(kt - mfs);
    num = e1s * num + e2s * vt;
    den = e1s * den + e2s;
    mx = mfs;
  }
  pn[idx] = num;
  pd[idx] = den;
  pm[idx] = mx;
}

// ---------------- WKV pass 2: sequential combine over chunks ---------------
// One thread per (b,h); stores each chunk's true initial state.
__global__ void wkv_pass2(const float* __restrict__ pn,
                          const float* __restrict__ pd,
                          const float* __restrict__ pm,
                          const float* __restrict__ tdec,
                          float* __restrict__ sn, float* __restrict__ sd,
                          float* __restrict__ sm, int H, int L) {
  int idx = blockIdx.x * blockDim.x + threadIdx.x;  // [0, B*H)
  int h = idx % H;
  int b = idx / H;
  const float Ltd = -__expf(tdec[h]) * (float)L;
  float num = 0.f, den = 0.f, mx = -1e38f;
#pragma unroll
  for (int c = 0; c < WKV_C; ++c) {
    size_t o = ((size_t)b * WKV_C + c) * H + h;
    sn[o] = num;
    sd[o] = den;
    sm[o] = mx;
    float mtd = mx + Ltd;
    float cm = pm[o];
    float mnew = fmaxf(mtd, cm);
    float e1 = __expf(mtd - mnew);
    float e2 = __expf(cm - mnew);
    num = e1 * num + e2 * pn[o];
    den = e1 * den + e2 * pd[o];
    mx = mnew;
  }
}

// ---------------- WKV pass 3: replay chunk from true state, emit y ---------
// y aliases rr (in-place, read-before-write per element per thread).
__global__ void wkv_pass3(const unsigned short* __restrict__ kk,
                          const unsigned short* __restrict__ vv,
                          const unsigned short* rr,
                          const float* __restrict__ sn,
                          const float* __restrict__ sd,
                          const float* __restrict__ sm,
                          const float* __restrict__ tdec,
                          const float* __restrict__ tfir, unsigned short* y,
                          int T, int H, int L) {
  int idx = blockIdx.x * blockDim.x + threadIdx.x;  // [0, B*C*H)
  int h = idx % H;
  int bc = idx / H;
  int c = bc % WKV_C;
  int b = bc / WKV_C;
  const float td = -__expf(tdec[h]);
  const float tf = tfir[h];
  float num = sn[idx], den = sd[idx], mx = sm[idx];
  size_t base = ((size_t)b * T + (size_t)c * L) * H + h;
  const unsigned short* kp = kk + base;
  const unsigned short* vp = vv + base;
  const unsigned short* rp = rr + base;
  unsigned short* yp = y + base;
#pragma unroll 4
  for (int t = 0; t < L; ++t) {
    size_t o = (size_t)t * H;
    float kt = h2f(kp[o]);
    float vt = h2f(vp[o]);
    float rt = h2f(rp[o]);
    float ktf = kt + tf;
    float mfo = fmaxf(mx, ktf);
    float e1 = __expf(mx - mfo);
    float e2 = __expf(ktf - mfo);
    float out = __fdividef(e1 * num + e2 * vt, e1 * den + e2);
    yp[o] = f2bf(rt * out);
    float mtd = mx + td;
    float mfs = fmaxf(mtd, kt);
    float e1s = __expf(mtd - mfs);
    float e2s = __expf(kt - mfs);
    num = e1s * num + e2s * vt;
    den = e1s * den + e2s;
    mx = mfs;
  }
}

// ---------------------------------------------------------------------------
extern "C" void kernel_launch(void* const* d_in, const int* in_sizes, int n_in,
                              void* d_out, int out_size, void* d_ws,
                              size_t ws_size, hipStream_t stream) {
  const int Bb = 4, T = 2048, H = 2048;
  const int M = Bb * T;      // 8192
  const int L = T / WKV_C;   // 64

  const float* hidden = (const float*)d_in[0];
  const float* time_decay = (const float*)d_in[1];
  const float* time_first = (const float*)d_in[2];
  const float* tmk = (const float*)d_in[3];
  const float* tmv = (const float*)d_in[4];
  const float* tmr = (const float*)d_in[5];
  const float* Wk = (const float*)d_in[6];
  const float* Wv = (const float*)d_in[7];
  const float* Wr = (const float*)d_in[8];
  const float* Wo = (const float*)d_in[9];
  float* out = (float*)d_out;

  const size_t szWT = (size_t)H * H * 2;   // 8.4 MB  (bf16, reused x4)
  const size_t szMH = (size_t)M * H * 2;   // 33.5 MB (bf16/fp16 M x H)
  const size_t need = szWT + 4 * szMH + 1024;
  if (ws_size < need) return;  // diagnostic guard: clean absmax fail, no fault

  char* ws = (char*)d_ws;
  size_t off = 0;
  auto alloc = [&](size_t bytes) {
    char* p = ws + off;
    off += (bytes + 255) & ~(size_t)255;
    return p;
  };
  unsigned short* WT = (unsigned short*)alloc(szWT);
  unsigned short* xbuf = (unsigned short*)alloc(szMH);  // mix out, reused x3
  unsigned short* kbuf = (unsigned short*)alloc(szMH);  // fp16
  unsigned short* vbuf = (unsigned short*)alloc(szMH);  // fp16
  unsigned short* rbuf = (unsigned short*)alloc(szMH);  // fp16; y (bf16) in-place

  // chunk-scan arrays live inside xbuf (dead after the last mix+GEMM):
  // 6 arrays of B*WKV_C*H floats = 6 MB << 33.5 MB.
  const size_t nCH = (size_t)Bb * WKV_C * H;  // 262144
  float* pn = (float*)xbuf;
  float* pd = pn + nCH;
  float* pm = pd + nCH;
  float* sn = pm + nCH;
  float* sd = sn + nCH;
  float* sm = sd + nCH;

  const dim3 txG(H / 32, H / 32), txB(32, 8);
  const int H4 = H / 4;
  const dim3 mixG((M * H4) / 256), mixB(256);
  const dim3 gmG(H / 128, M / 128), gmB(256);

  // k path
  transpose_cast<<<txG, txB, 0, stream>>>(Wk, WT, H);
  mix_kernel<<<mixG, mixB, 0, stream>>>((const float4*)hidden,
                                        (const float4*)tmk, (ushort4*)xbuf, T, H4);
  gemm_bt<<<gmG, gmB, 0, stream>>>(xbuf, WT, kbuf, H, H, MODE_F16);
  // v path
  transpose_cast<<<txG, txB, 0, stream>>>(Wv, WT, H);
  mix_kernel<<<mixG, mixB, 0, stream>>>((const float4*)hidden,
                                        (const float4*)tmv, (ushort4*)xbuf, T, H4);
  gemm_bt<<<gmG, gmB, 0, stream>>>(xbuf, WT, vbuf, H, H, MODE_F16);
  // r path (sigmoid fused)
  transpose_cast<<<txG, txB, 0, stream>>>(Wr, WT, H);
  mix_kernel<<<mixG, mixB, 0, stream>>>((const float4*)hidden,
                                        (const float4*)tmr, (ushort4*)xbuf, T, H4);
  gemm_bt<<<gmG, gmB, 0, stream>>>(xbuf, WT, rbuf, H, H, MODE_F16_SIG);

  // WKV chunked parallel scan (xbuf now dead -> chunk arrays live there)
  const int nThreads1 = Bb * WKV_C * H;  // 262144
  wkv_pass1<<<dim3(nThreads1 / 256), dim3(256), 0, stream>>>(
      kbuf, vbuf, time_decay, pn, pd, pm, T, H, L);
  wkv_pass2<<<dim3((Bb * H) / 256), dim3(256), 0, stream>>>(
      pn, pd, pm, time_decay, sn, sd, sm, H, L);
  wkv_pass3<<<dim3(nThreads1 / 256), dim3(256), 0, stream>>>(
      kbuf, vbuf, rbuf, sn, sd, sm, time_decay, time_first, rbuf, T, H, L);

  // output GEMM: out = y @ Wo (fp32 out)
  transpose_cast<<<txG, txB, 0, stream>>>(Wo, WT, H);
  gemm_bt<<<gmG, gmB, 0, stream>>>(rbuf, WT, out, H, H, MODE_F32);
}

// Round 4
// 643.706 us; speedup vs baseline: 1.5931x; 1.1422x over previous
//
#include <hip/hip_runtime.h>
#include <hip/hip_bf16.h>
#include <stdint.h>

// ---------------------------------------------------------------------------
// RWKV self-attention: per-stage mix -> GEMM (bf16 MFMA) x3 -> WKV -> out GEMM
// B=4, T=2048, H=2048.
// GEMM: 128x128 tile, BK=64 (32 KB LDS), 16x16x32 bf16 MFMA,
// global_load_lds width=16, XOR-swizzled LDS (kb_phys = kb ^ (row&7)) so
// fragment ds_read_b128 are bank-conflict-free (R3: 8.4M conflict cycles).
// WKV: 3-pass chunked parallel scan (C=32 chunks of L=64).
// Workspace: WT 8.4MB + x 33.5MB + k/v/r(fp16) 100.7MB = 142.6 MB.
// ---------------------------------------------------------------------------

typedef short short8 __attribute__((ext_vector_type(8)));   // 8 bf16 (4 VGPRs)
typedef float f32x4 __attribute__((ext_vector_type(4)));

#define WKV_C 32  // chunks per sequence (L = T/WKV_C = 64)

__device__ __forceinline__ void gld_lds16(const void* gptr, void* lptr) {
  void* g = const_cast<void*>(gptr);
  __builtin_amdgcn_global_load_lds(
      (__attribute__((address_space(1))) void*)g,
      (__attribute__((address_space(3))) void*)lptr, 16, 0, 0);
}

__device__ __forceinline__ unsigned short f2bf(float f) {
  __bf16 b = (__bf16)f;
  return __builtin_bit_cast(unsigned short, b);
}
__device__ __forceinline__ unsigned short f2h(float f) {
  _Float16 h = (_Float16)f;
  return __builtin_bit_cast(unsigned short, h);
}
__device__ __forceinline__ float h2f(unsigned short u) {
  return (float)__builtin_bit_cast(_Float16, u);
}

// ---------------- weight transpose + fp32->bf16 cast -----------------------
__global__ void transpose_cast(const float* __restrict__ W,
                               unsigned short* __restrict__ WT, int n) {
  __shared__ float tile[32][33];
  const int tx = threadIdx.x, ty = threadIdx.y;
  const int x = blockIdx.x * 32 + tx;
#pragma unroll
  for (int j = 0; j < 32; j += 8) {
    int row = blockIdx.y * 32 + ty + j;
    tile[ty + j][tx] = W[(size_t)row * n + x];
  }
  __syncthreads();
#pragma unroll
  for (int j = 0; j < 32; j += 8) {
    int orow = blockIdx.x * 32 + ty + j;  // n index
    int ocol = blockIdx.y * 32 + tx;      // k index
    WT[(size_t)orow * n + ocol] = f2bf(tile[tx][ty + j]);
  }
}

// ---------------- time-shift mix (fp32 in, bf16 out) -----------------------
__global__ void mix_kernel(const float4* __restrict__ hid,
                           const float4* __restrict__ m4,
                           ushort4* __restrict__ x, int T, int H4) {
  size_t idx = (size_t)blockIdx.x * blockDim.x + threadIdx.x;
  int c4 = (int)(idx % H4);
  int t = (int)(idx / H4) % T;
  float4 h = hid[idx];
  float4 p = make_float4(0.f, 0.f, 0.f, 0.f);
  if (t != 0) p = hid[idx - H4];
  float4 m = m4[c4];
  ushort4 o;
  o.x = f2bf(h.x * m.x + p.x * (1.f - m.x));
  o.y = f2bf(h.y * m.y + p.y * (1.f - m.y));
  o.z = f2bf(h.z * m.z + p.z * (1.f - m.z));
  o.w = f2bf(h.w * m.w + p.w * (1.f - m.w));
  x[idx] = o;
}

// ---------------- bf16 MFMA GEMM: C[MxN] = A[MxK] * Bt[NxK]^T --------------
#define MODE_F32 0
#define MODE_F16 1
#define MODE_F16_SIG 2

__global__ __launch_bounds__(256) void gemm_bt(
    const unsigned short* __restrict__ A, const unsigned short* __restrict__ Bt,
    void* __restrict__ Cv, int N, int K, int mode) {
  // BK=64: tile is 128 rows x 64 cols bf16 = 16 KB per operand.
  __shared__ unsigned short lta[128 * 64];
  __shared__ unsigned short ltb[128 * 64];

  const int tid = threadIdx.x;
  const int lane = tid & 63;
  const int wave = tid >> 6;
  const int wm = wave >> 1, wn = wave & 1;
  const int quad = lane >> 4, lm = lane & 15;
  const int sw = lm & 7;  // row&7 for fragment rows (row = base16*16 + lm)

  const int mBase = blockIdx.y * 128;
  const int nBase = blockIdx.x * 128;

  // staging: 1024 chunks of 16B per tile; chunk c -> row c>>3, phys kb c&7.
  // LDS dst byte = c*16 (lane-contiguous, required by global_load_lds).
  // Global source kb = (c&7) ^ (row&7)  -> XOR-swizzled LDS layout.
  const unsigned short* AgS[4];
  const unsigned short* BgS[4];
  unsigned short* LaS[4];
  unsigned short* LbS[4];
#pragma unroll
  for (int j = 0; j < 4; ++j) {
    int c = tid + j * 256;
    int row = c >> 3;
    int kb = (c & 7) ^ (row & 7);
    AgS[j] = A + (size_t)(mBase + row) * K + kb * 8;
    BgS[j] = Bt + (size_t)(nBase + row) * K + kb * 8;
    LaS[j] = lta + c * 8;
    LbS[j] = ltb + c * 8;
  }

  // fragment LDS pointers (loop-invariant): element (row, kk*32+quad*8+j)
  // stored at row*64 + ((kk*4+quad) ^ (row&7))*8.
  const unsigned short* lap[2][4];
  const unsigned short* lbp[2][4];
#pragma unroll
  for (int kk = 0; kk < 2; ++kk)
#pragma unroll
    for (int i = 0; i < 4; ++i) {
      int chA = (kk * 4 + quad) ^ sw;
      lap[kk][i] = lta + (wm * 64 + i * 16 + lm) * 64 + chA * 8;
      lbp[kk][i] = ltb + (wn * 64 + i * 16 + lm) * 64 + chA * 8;
    }

  f32x4 acc[4][4];
#pragma unroll
  for (int i = 0; i < 4; ++i)
#pragma unroll
    for (int j = 0; j < 4; ++j) {
      f32x4 zz = {0.f, 0.f, 0.f, 0.f};
      acc[i][j] = zz;
    }

  for (int k0 = 0; k0 < K; k0 += 64) {
    __syncthreads();
#pragma unroll
    for (int j = 0; j < 4; ++j) gld_lds16(AgS[j] + k0, LaS[j]);
#pragma unroll
    for (int j = 0; j < 4; ++j) gld_lds16(BgS[j] + k0, LbS[j]);
    __syncthreads();
#pragma unroll
    for (int kk = 0; kk < 2; ++kk) {
      short8 aF[4], bF[4];
#pragma unroll
      for (int i = 0; i < 4; ++i) aF[i] = *(const short8*)lap[kk][i];
#pragma unroll
      for (int j = 0; j < 4; ++j) bF[j] = *(const short8*)lbp[kk][j];
#pragma unroll
      for (int i = 0; i < 4; ++i)
#pragma unroll
        for (int j = 0; j < 4; ++j)
          acc[i][j] = __builtin_amdgcn_mfma_f32_16x16x32_bf16(
              aF[i], bF[j], acc[i][j], 0, 0, 0);
    }
  }

  // epilogue: C/D layout col=lane&15, row=quad*4+reg  [m89/m91 verified]
#pragma unroll
  for (int i = 0; i < 4; ++i) {
#pragma unroll
    for (int j = 0; j < 4; ++j) {
      const int r0 = mBase + wm * 64 + i * 16 + quad * 4;
      const int cc = nBase + wn * 64 + j * 16 + lm;
#pragma unroll
      for (int rg = 0; rg < 4; ++rg) {
        float x = acc[i][j][rg];
        size_t off = (size_t)(r0 + rg) * N + cc;
        if (mode == MODE_F32) {
          ((float*)Cv)[off] = x;
        } else {
          if (mode == MODE_F16_SIG) x = 1.0f / (1.0f + __expf(-x));
          ((unsigned short*)Cv)[off] = f2h(x);
        }
      }
    }
  }
}

// ---------------- WKV pass 1: per-chunk summary from zero state ------------
__global__ void wkv_pass1(const unsigned short* __restrict__ kk,
                          const unsigned short* __restrict__ vv,
                          const float* __restrict__ tdec,
                          float* __restrict__ pn, float* __restrict__ pd,
                          float* __restrict__ pm, int T, int H, int L) {
  int idx = blockIdx.x * blockDim.x + threadIdx.x;  // [0, B*C*H)
  int h = idx % H;
  int bc = idx / H;
  int c = bc % WKV_C;
  int b = bc / WKV_C;
  const float td = -__expf(tdec[h]);
  size_t base = ((size_t)b * T + (size_t)c * L) * H + h;
  const unsigned short* kp = kk + base;
  const unsigned short* vp = vv + base;
  float num = 0.f, den = 0.f, mx = -1e38f;
#pragma unroll 8
  for (int t = 0; t < L; ++t) {
    float kt = h2f(kp[(size_t)t * H]);
    float vt = h2f(vp[(size_t)t * H]);
    float mtd = mx + td;
    float mfs = fmaxf(mtd, kt);
    float e1s = __expf(mtd - mfs);
    float e2s = __expf(kt - mfs);
    num = e1s * num + e2s * vt;
    den = e1s * den + e2s;
    mx = mfs;
  }
  pn[idx] = num;
  pd[idx] = den;
  pm[idx] = mx;
}

// ---------------- WKV pass 2: sequential combine over chunks ---------------
__global__ void wkv_pass2(const float* __restrict__ pn,
                          const float* __restrict__ pd,
                          const float* __restrict__ pm,
                          const float* __restrict__ tdec,
                          float* __restrict__ sn, float* __restrict__ sd,
                          float* __restrict__ sm, int H, int L) {
  int idx = blockIdx.x * blockDim.x + threadIdx.x;  // [0, B*H)
  int h = idx % H;
  int b = idx / H;
  const float Ltd = -__expf(tdec[h]) * (float)L;
  float num = 0.f, den = 0.f, mx = -1e38f;
#pragma unroll
  for (int c = 0; c < WKV_C; ++c) {
    size_t o = ((size_t)b * WKV_C + c) * H + h;
    sn[o] = num;
    sd[o] = den;
    sm[o] = mx;
    float mtd = mx + Ltd;
    float cm = pm[o];
    float mnew = fmaxf(mtd, cm);
    float e1 = __expf(mtd - mnew);
    float e2 = __expf(cm - mnew);
    num = e1 * num + e2 * pn[o];
    den = e1 * den + e2 * pd[o];
    mx = mnew;
  }
}

// ---------------- WKV pass 3: replay chunk from true state, emit y ---------
__global__ void wkv_pass3(const unsigned short* __restrict__ kk,
                          const unsigned short* __restrict__ vv,
                          const unsigned short* rr,
                          const float* __restrict__ sn,
                          const float* __restrict__ sd,
                          const float* __restrict__ sm,
                          const float* __restrict__ tdec,
                          const float* __restrict__ tfir, unsigned short* y,
                          int T, int H, int L) {
  int idx = blockIdx.x * blockDim.x + threadIdx.x;  // [0, B*C*H)
  int h = idx % H;
  int bc = idx / H;
  int c = bc % WKV_C;
  int b = bc / WKV_C;
  const float td = -__expf(tdec[h]);
  const float tf = tfir[h];
  float num = sn[idx], den = sd[idx], mx = sm[idx];
  size_t base = ((size_t)b * T + (size_t)c * L) * H + h;
  const unsigned short* kp = kk + base;
  const unsigned short* vp = vv + base;
  const unsigned short* rp = rr + base;
  unsigned short* yp = y + base;
#pragma unroll 4
  for (int t = 0; t < L; ++t) {
    size_t o = (size_t)t * H;
    float kt = h2f(kp[o]);
    float vt = h2f(vp[o]);
    float rt = h2f(rp[o]);
    float ktf = kt + tf;
    float mfo = fmaxf(mx, ktf);
    float e1 = __expf(mx - mfo);
    float e2 = __expf(ktf - mfo);
    float out = __fdividef(e1 * num + e2 * vt, e1 * den + e2);
    yp[o] = f2bf(rt * out);
    float mtd = mx + td;
    float mfs = fmaxf(mtd, kt);
    float e1s = __expf(mtd - mfs);
    float e2s = __expf(kt - mfs);
    num = e1s * num + e2s * vt;
    den = e1s * den + e2s;
    mx = mfs;
  }
}

// ---------------------------------------------------------------------------
extern "C" void kernel_launch(void* const* d_in, const int* in_sizes, int n_in,
                              void* d_out, int out_size, void* d_ws,
                              size_t ws_size, hipStream_t stream) {
  const int Bb = 4, T = 2048, H = 2048;
  const int M = Bb * T;      // 8192
  const int L = T / WKV_C;   // 64

  const float* hidden = (const float*)d_in[0];
  const float* time_decay = (const float*)d_in[1];
  const float* time_first = (const float*)d_in[2];
  const float* tmk = (const float*)d_in[3];
  const float* tmv = (const float*)d_in[4];
  const float* tmr = (const float*)d_in[5];
  const float* Wk = (const float*)d_in[6];
  const float* Wv = (const float*)d_in[7];
  const float* Wr = (const float*)d_in[8];
  const float* Wo = (const float*)d_in[9];
  float* out = (float*)d_out;

  const size_t szWT = (size_t)H * H * 2;   // 8.4 MB  (bf16, reused x4)
  const size_t szMH = (size_t)M * H * 2;   // 33.5 MB (bf16/fp16 M x H)
  const size_t need = szWT + 4 * szMH + 1024;
  if (ws_size < need) return;  // diagnostic guard

  char* ws = (char*)d_ws;
  size_t off = 0;
  auto alloc = [&](size_t bytes) {
    char* p = ws + off;
    off += (bytes + 255) & ~(size_t)255;
    return p;
  };
  unsigned short* WT = (unsigned short*)alloc(szWT);
  unsigned short* xbuf = (unsigned short*)alloc(szMH);  // mix out, reused x3
  unsigned short* kbuf = (unsigned short*)alloc(szMH);  // fp16
  unsigned short* vbuf = (unsigned short*)alloc(szMH);  // fp16
  unsigned short* rbuf = (unsigned short*)alloc(szMH);  // fp16; y in-place

  // chunk-scan arrays live inside xbuf (dead after the last mix+GEMM): 6 MB.
  const size_t nCH = (size_t)Bb * WKV_C * H;  // 262144
  float* pn = (float*)xbuf;
  float* pd = pn + nCH;
  float* pm = pd + nCH;
  float* sn = pm + nCH;
  float* sd = sn + nCH;
  float* sm = sd + nCH;

  const dim3 txG(H / 32, H / 32), txB(32, 8);
  const int H4 = H / 4;
  const dim3 mixG((M * H4) / 256), mixB(256);
  const dim3 gmG(H / 128, M / 128), gmB(256);

  // k path
  transpose_cast<<<txG, txB, 0, stream>>>(Wk, WT, H);
  mix_kernel<<<mixG, mixB, 0, stream>>>((const float4*)hidden,
                                        (const float4*)tmk, (ushort4*)xbuf, T, H4);
  gemm_bt<<<gmG, gmB, 0, stream>>>(xbuf, WT, kbuf, H, H, MODE_F16);
  // v path
  transpose_cast<<<txG, txB, 0, stream>>>(Wv, WT, H);
  mix_kernel<<<mixG, mixB, 0, stream>>>((const float4*)hidden,
                                        (const float4*)tmv, (ushort4*)xbuf, T, H4);
  gemm_bt<<<gmG, gmB, 0, stream>>>(xbuf, WT, vbuf, H, H, MODE_F16);
  // r path (sigmoid fused)
  transpose_cast<<<txG, txB, 0, stream>>>(Wr, WT, H);
  mix_kernel<<<mixG, mixB, 0, stream>>>((const float4*)hidden,
                                        (const float4*)tmr, (ushort4*)xbuf, T, H4);
  gemm_bt<<<gmG, gmB, 0, stream>>>(xbuf, WT, rbuf, H, H, MODE_F16_SIG);

  // WKV chunked parallel scan (xbuf now dead -> chunk arrays live there)
  const int nThreads1 = Bb * WKV_C * H;  // 262144
  wkv_pass1<<<dim3(nThreads1 / 256), dim3(256), 0, stream>>>(
      kbuf, vbuf, time_decay, pn, pd, pm, T, H, L);
  wkv_pass2<<<dim3((Bb * H) / 256), dim3(256), 0, stream>>>(
      pn, pd, pm, time_decay, sn, sd, sm, H, L);
  wkv_pass3<<<dim3(nThreads1 / 256), dim3(256), 0, stream>>>(
      kbuf, vbuf, rbuf, sn, sd, sm, time_decay, time_first, rbuf, T, H, L);

  // output GEMM: out = y @ Wo (fp32 out)
  transpose_cast<<<txG, txB, 0, stream>>>(Wo, WT, H);
  gemm_bt<<<gmG, gmB, 0, stream>>>(rbuf, WT, out, H, H, MODE_F32);
}

// Round 5
// 591.710 us; speedup vs baseline: 1.7331x; 1.0879x over previous
//
#include <hip/hip_runtime.h>
#include <hip/hip_bf16.h>
#include <stdint.h>

// ---------------------------------------------------------------------------
// RWKV self-attention: fused mix -> GEMM (bf16 MFMA) x3 -> WKV -> out GEMM
// B=4, T=2048, H=2048.
// GEMM: 128x128 tile, BK=64, 16x16x32 bf16 MFMA, global_load_lds width=16,
// XOR-swizzled LDS (conflict-free, R4: SQ_LDS_BANK_CONFLICT=0), plus
// XCD-patch block swizzle (each lin%8 class = 8Mx16N tile patch) for L2 reuse.
// WKV: 3-pass chunked parallel scan (C=32 chunks of L=64).
// Workspace (unchanged, known-safe): WT 8.4MB + 4 x 33.5MB = 142.6 MB.
//   A1=xk, A2=xv, A3=xr, A4=kbuf; vbuf=A1 (xk dead), rbuf=A2 (xv dead),
//   chunk arrays in A3 (xr dead), y in-place over rbuf.
// ---------------------------------------------------------------------------

typedef short short8 __attribute__((ext_vector_type(8)));   // 8 bf16 (4 VGPRs)
typedef float f32x4 __attribute__((ext_vector_type(4)));

#define WKV_C 32  // chunks per sequence (L = T/WKV_C = 64)

__device__ __forceinline__ void gld_lds16(const void* gptr, void* lptr) {
  void* g = const_cast<void*>(gptr);
  __builtin_amdgcn_global_load_lds(
      (__attribute__((address_space(1))) void*)g,
      (__attribute__((address_space(3))) void*)lptr, 16, 0, 0);
}

__device__ __forceinline__ unsigned short f2bf(float f) {
  __bf16 b = (__bf16)f;
  return __builtin_bit_cast(unsigned short, b);
}
__device__ __forceinline__ unsigned short f2h(float f) {
  _Float16 h = (_Float16)f;
  return __builtin_bit_cast(unsigned short, h);
}
__device__ __forceinline__ float h2f(unsigned short u) {
  return (float)__builtin_bit_cast(_Float16, u);
}

// ---------------- weight transpose + fp32->bf16 cast -----------------------
__global__ void transpose_cast(const float* __restrict__ W,
                               unsigned short* __restrict__ WT, int n) {
  __shared__ float tile[32][33];
  const int tx = threadIdx.x, ty = threadIdx.y;
  const int x = blockIdx.x * 32 + tx;
#pragma unroll
  for (int j = 0; j < 32; j += 8) {
    int row = blockIdx.y * 32 + ty + j;
    tile[ty + j][tx] = W[(size_t)row * n + x];
  }
  __syncthreads();
#pragma unroll
  for (int j = 0; j < 32; j += 8) {
    int orow = blockIdx.x * 32 + ty + j;  // n index
    int ocol = blockIdx.y * 32 + tx;      // k index
    WT[(size_t)orow * n + ocol] = f2bf(tile[tx][ty + j]);
  }
}

// ---------------- fused time-shift mix: hidden read ONCE, 3 outputs --------
__global__ void mix3_kernel(const float4* __restrict__ hid,
                            const float4* __restrict__ mk4,
                            const float4* __restrict__ mv4,
                            const float4* __restrict__ mr4,
                            ushort4* __restrict__ xk, ushort4* __restrict__ xv,
                            ushort4* __restrict__ xr, int T, int H4) {
  size_t idx = (size_t)blockIdx.x * blockDim.x + threadIdx.x;
  int c4 = (int)(idx % H4);
  int t = (int)(idx / H4) % T;
  float4 h = hid[idx];
  float4 p = make_float4(0.f, 0.f, 0.f, 0.f);
  if (t != 0) p = hid[idx - H4];
  float4 mk = mk4[c4], mv = mv4[c4], mr = mr4[c4];
  ushort4 ok, ov, orr;
  ok.x = f2bf(h.x * mk.x + p.x * (1.f - mk.x));
  ok.y = f2bf(h.y * mk.y + p.y * (1.f - mk.y));
  ok.z = f2bf(h.z * mk.z + p.z * (1.f - mk.z));
  ok.w = f2bf(h.w * mk.w + p.w * (1.f - mk.w));
  ov.x = f2bf(h.x * mv.x + p.x * (1.f - mv.x));
  ov.y = f2bf(h.y * mv.y + p.y * (1.f - mv.y));
  ov.z = f2bf(h.z * mv.z + p.z * (1.f - mv.z));
  ov.w = f2bf(h.w * mv.w + p.w * (1.f - mv.w));
  orr.x = f2bf(h.x * mr.x + p.x * (1.f - mr.x));
  orr.y = f2bf(h.y * mr.y + p.y * (1.f - mr.y));
  orr.z = f2bf(h.z * mr.z + p.z * (1.f - mr.z));
  orr.w = f2bf(h.w * mr.w + p.w * (1.f - mr.w));
  xk[idx] = ok;
  xv[idx] = ov;
  xr[idx] = orr;
}

// ---------------- bf16 MFMA GEMM: C[MxN] = A[MxK] * Bt[NxK]^T --------------
#define MODE_F32 0
#define MODE_F16 1
#define MODE_F16_SIG 2

__global__ __launch_bounds__(256) void gemm_bt(
    const unsigned short* __restrict__ A, const unsigned short* __restrict__ Bt,
    void* __restrict__ Cv, int N, int K, int mode) {
  __shared__ unsigned short lta[128 * 64];
  __shared__ unsigned short ltb[128 * 64];

  const int tid = threadIdx.x;
  const int lane = tid & 63;
  const int wave = tid >> 6;
  const int wm = wave >> 1, wn = wave & 1;
  const int quad = lane >> 4, lm = lane & 15;
  const int sw = lm & 7;

  // XCD-patch swizzle: lin%8 (assumed XCD round-robin) selects an 8-row
  // M-patch; within a class, q enumerates 8 rows x 16 cols compactly.
  // Bijection: grid (16, 64) -> (nTile 0..15, mTile 0..63).
  const int lin = blockIdx.y * 16 + blockIdx.x;
  const int cls = lin & 7;
  const int q = lin >> 3;            // 0..127
  const int mTile = cls * 8 + (q & 7);
  const int nTile = q >> 3;          // 0..15
  const int mBase = mTile * 128;
  const int nBase = nTile * 128;

  // staging: 1024 chunks of 16B per tile; chunk c -> row c>>3, phys kb c&7.
  // Global source kb = (c&7) ^ (row&7)  -> XOR-swizzled LDS layout.
  const unsigned short* AgS[4];
  const unsigned short* BgS[4];
  unsigned short* LaS[4];
  unsigned short* LbS[4];
#pragma unroll
  for (int j = 0; j < 4; ++j) {
    int c = tid + j * 256;
    int row = c >> 3;
    int kb = (c & 7) ^ (row & 7);
    AgS[j] = A + (size_t)(mBase + row) * K + kb * 8;
    BgS[j] = Bt + (size_t)(nBase + row) * K + kb * 8;
    LaS[j] = lta + c * 8;
    LbS[j] = ltb + c * 8;
  }

  // fragment LDS pointers: element (row, kk*32+quad*8+j) at
  // row*64 + ((kk*4+quad) ^ (row&7))*8.
  const unsigned short* lap[2][4];
  const unsigned short* lbp[2][4];
#pragma unroll
  for (int kk = 0; kk < 2; ++kk)
#pragma unroll
    for (int i = 0; i < 4; ++i) {
      int chA = (kk * 4 + quad) ^ sw;
      lap[kk][i] = lta + (wm * 64 + i * 16 + lm) * 64 + chA * 8;
      lbp[kk][i] = ltb + (wn * 64 + i * 16 + lm) * 64 + chA * 8;
    }

  f32x4 acc[4][4];
#pragma unroll
  for (int i = 0; i < 4; ++i)
#pragma unroll
    for (int j = 0; j < 4; ++j) {
      f32x4 zz = {0.f, 0.f, 0.f, 0.f};
      acc[i][j] = zz;
    }

  for (int k0 = 0; k0 < K; k0 += 64) {
    __syncthreads();
#pragma unroll
    for (int j = 0; j < 4; ++j) gld_lds16(AgS[j] + k0, LaS[j]);
#pragma unroll
    for (int j = 0; j < 4; ++j) gld_lds16(BgS[j] + k0, LbS[j]);
    __syncthreads();
#pragma unroll
    for (int kk = 0; kk < 2; ++kk) {
      short8 aF[4], bF[4];
#pragma unroll
      for (int i = 0; i < 4; ++i) aF[i] = *(const short8*)lap[kk][i];
#pragma unroll
      for (int j = 0; j < 4; ++j) bF[j] = *(const short8*)lbp[kk][j];
#pragma unroll
      for (int i = 0; i < 4; ++i)
#pragma unroll
        for (int j = 0; j < 4; ++j)
          acc[i][j] = __builtin_amdgcn_mfma_f32_16x16x32_bf16(
              aF[i], bF[j], acc[i][j], 0, 0, 0);
    }
  }

  // epilogue: C/D layout col=lane&15, row=quad*4+reg  [m89/m91 verified]
#pragma unroll
  for (int i = 0; i < 4; ++i) {
#pragma unroll
    for (int j = 0; j < 4; ++j) {
      const int r0 = mBase + wm * 64 + i * 16 + quad * 4;
      const int cc = nBase + wn * 64 + j * 16 + lm;
#pragma unroll
      for (int rg = 0; rg < 4; ++rg) {
        float x = acc[i][j][rg];
        size_t off = (size_t)(r0 + rg) * N + cc;
        if (mode == MODE_F32) {
          ((float*)Cv)[off] = x;
        } else {
          if (mode == MODE_F16_SIG) x = 1.0f / (1.0f + __expf(-x));
          ((unsigned short*)Cv)[off] = f2h(x);
        }
      }
    }
  }
}

// ---------------- WKV pass 1: per-chunk summary from zero state ------------
__global__ void wkv_pass1(const unsigned short* __restrict__ kk,
                          const unsigned short* __restrict__ vv,
                          const float* __restrict__ tdec,
                          float* __restrict__ pn, float* __restrict__ pd,
                          float* __restrict__ pm, int T, int H, int L) {
  int idx = blockIdx.x * blockDim.x + threadIdx.x;  // [0, B*C*H)
  int h = idx % H;
  int bc = idx / H;
  int c = bc % WKV_C;
  int b = bc / WKV_C;
  const float td = -__expf(tdec[h]);
  size_t base = ((size_t)b * T + (size_t)c * L) * H + h;
  const unsigned short* kp = kk + base;
  const unsigned short* vp = vv + base;
  float num = 0.f, den = 0.f, mx = -1e38f;
#pragma unroll 8
  for (int t = 0; t < L; ++t) {
    float kt = h2f(kp[(size_t)t * H]);
    float vt = h2f(vp[(size_t)t * H]);
    float mtd = mx + td;
    float mfs = fmaxf(mtd, kt);
    float e1s = __expf(mtd - mfs);
    float e2s = __expf(kt - mfs);
    num = e1s * num + e2s * vt;
    den = e1s * den + e2s;
    mx = mfs;
  }
  pn[idx] = num;
  pd[idx] = den;
  pm[idx] = mx;
}

// ---------------- WKV pass 2: sequential combine over chunks ---------------
__global__ void wkv_pass2(const float* __restrict__ pn,
                          const float* __restrict__ pd,
                          const float* __restrict__ pm,
                          const float* __restrict__ tdec,
                          float* __restrict__ sn, float* __restrict__ sd,
                          float* __restrict__ sm, int H, int L) {
  int idx = blockIdx.x * blockDim.x + threadIdx.x;  // [0, B*H)
  int h = idx % H;
  int b = idx / H;
  const float Ltd = -__expf(tdec[h]) * (float)L;
  float num = 0.f, den = 0.f, mx = -1e38f;
#pragma unroll
  for (int c = 0; c < WKV_C; ++c) {
    size_t o = ((size_t)b * WKV_C + c) * H + h;
    sn[o] = num;
    sd[o] = den;
    sm[o] = mx;
    float mtd = mx + Ltd;
    float cm = pm[o];
    float mnew = fmaxf(mtd, cm);
    float e1 = __expf(mtd - mnew);
    float e2 = __expf(cm - mnew);
    num = e1 * num + e2 * pn[o];
    den = e1 * den + e2 * pd[o];
    mx = mnew;
  }
}

// ---------------- WKV pass 3: replay chunk from true state, emit y ---------
__global__ void wkv_pass3(const unsigned short* __restrict__ kk,
                          const unsigned short* __restrict__ vv,
                          const unsigned short* rr,
                          const float* __restrict__ sn,
                          const float* __restrict__ sd,
                          const float* __restrict__ sm,
                          const float* __restrict__ tdec,
                          const float* __restrict__ tfir, unsigned short* y,
                          int T, int H, int L) {
  int idx = blockIdx.x * blockDim.x + threadIdx.x;  // [0, B*C*H)
  int h = idx % H;
  int bc = idx / H;
  int c = bc % WKV_C;
  int b = bc / WKV_C;
  const float td = -__expf(tdec[h]);
  const float tf = tfir[h];
  float num = sn[idx], den = sd[idx], mx = sm[idx];
  size_t base = ((size_t)b * T + (size_t)c * L) * H + h;
  const unsigned short* kp = kk + base;
  const unsigned short* vp = vv + base;
  const unsigned short* rp = rr + base;
  unsigned short* yp = y + base;
#pragma unroll 4
  for (int t = 0; t < L; ++t) {
    size_t o = (size_t)t * H;
    float kt = h2f(kp[o]);
    float vt = h2f(vp[o]);
    float rt = h2f(rp[o]);
    float ktf = kt + tf;
    float mfo = fmaxf(mx, ktf);
    float e1 = __expf(mx - mfo);
    float e2 = __expf(ktf - mfo);
    float out = __fdividef(e1 * num + e2 * vt, e1 * den + e2);
    yp[o] = f2bf(rt * out);
    float mtd = mx + td;
    float mfs = fmaxf(mtd, kt);
    float e1s = __expf(mtd - mfs);
    float e2s = __expf(kt - mfs);
    num = e1s * num + e2s * vt;
    den = e1s * den + e2s;
    mx = mfs;
  }
}

// ---------------------------------------------------------------------------
extern "C" void kernel_launch(void* const* d_in, const int* in_sizes, int n_in,
                              void* d_out, int out_size, void* d_ws,
                              size_t ws_size, hipStream_t stream) {
  const int Bb = 4, T = 2048, H = 2048;
  const int M = Bb * T;      // 8192
  const int L = T / WKV_C;   // 64

  const float* hidden = (const float*)d_in[0];
  const float* time_decay = (const float*)d_in[1];
  const float* time_first = (const float*)d_in[2];
  const float* tmk = (const float*)d_in[3];
  const float* tmv = (const float*)d_in[4];
  const float* tmr = (const float*)d_in[5];
  const float* Wk = (const float*)d_in[6];
  const float* Wv = (const float*)d_in[7];
  const float* Wr = (const float*)d_in[8];
  const float* Wo = (const float*)d_in[9];
  float* out = (float*)d_out;

  const size_t szWT = (size_t)H * H * 2;   // 8.4 MB
  const size_t szMH = (size_t)M * H * 2;   // 33.5 MB
  const size_t need = szWT + 4 * szMH + 1024;
  if (ws_size < need) return;  // diagnostic guard

  char* ws = (char*)d_ws;
  size_t off = 0;
  auto alloc = [&](size_t bytes) {
    char* p = ws + off;
    off += (bytes + 255) & ~(size_t)255;
    return p;
  };
  unsigned short* WT = (unsigned short*)alloc(szWT);
  unsigned short* A1 = (unsigned short*)alloc(szMH);  // xk, later vbuf
  unsigned short* A2 = (unsigned short*)alloc(szMH);  // xv, later rbuf/y
  unsigned short* A3 = (unsigned short*)alloc(szMH);  // xr, later chunk arrays
  unsigned short* A4 = (unsigned short*)alloc(szMH);  // kbuf

  unsigned short* xk = A1;
  unsigned short* xv = A2;
  unsigned short* xr = A3;
  unsigned short* kbuf = A4;
  unsigned short* vbuf = A1;  // xk dead after GEMM-k
  unsigned short* rbuf = A2;  // xv dead after GEMM-v; y in-place later

  // chunk-scan arrays in A3 (xr dead after GEMM-r): 6 MB << 33.5 MB.
  const size_t nCH = (size_t)Bb * WKV_C * H;  // 262144
  float* pn = (float*)A3;
  float* pd = pn + nCH;
  float* pm = pd + nCH;
  float* sn = pm + nCH;
  float* sd = sn + nCH;
  float* sm = sd + nCH;

  const dim3 txG(H / 32, H / 32), txB(32, 8);
  const int H4 = H / 4;
  const dim3 gmG(H / 128, M / 128), gmB(256);

  // fused mix (hidden read once)
  mix3_kernel<<<dim3((M * H4) / 256), dim3(256), 0, stream>>>(
      (const float4*)hidden, (const float4*)tmk, (const float4*)tmv,
      (const float4*)tmr, (ushort4*)xk, (ushort4*)xv, (ushort4*)xr, T, H4);

  // k path
  transpose_cast<<<txG, txB, 0, stream>>>(Wk, WT, H);
  gemm_bt<<<gmG, gmB, 0, stream>>>(xk, WT, kbuf, H, H, MODE_F16);
  // v path (writes over dead xk)
  transpose_cast<<<txG, txB, 0, stream>>>(Wv, WT, H);
  gemm_bt<<<gmG, gmB, 0, stream>>>(xv, WT, vbuf, H, H, MODE_F16);
  // r path (sigmoid fused; writes over dead xv)
  transpose_cast<<<txG, txB, 0, stream>>>(Wr, WT, H);
  gemm_bt<<<gmG, gmB, 0, stream>>>(xr, WT, rbuf, H, H, MODE_F16_SIG);

  // WKV chunked parallel scan (xr region now dead -> chunk arrays there)
  const int nThreads1 = Bb * WKV_C * H;  // 262144
  wkv_pass1<<<dim3(nThreads1 / 256), dim3(256), 0, stream>>>(
      kbuf, vbuf, time_decay, pn, pd, pm, T, H, L);
  wkv_pass2<<<dim3((Bb * H) / 256), dim3(256), 0, stream>>>(
      pn, pd, pm, time_decay, sn, sd, sm, H, L);
  wkv_pass3<<<dim3(nThreads1 / 256), dim3(256), 0, stream>>>(
      kbuf, vbuf, rbuf, sn, sd, sm, time_decay, time_first, rbuf, T, H, L);

  // output GEMM: out = y @ Wo (fp32 out)
  transpose_cast<<<txG, txB, 0, stream>>>(Wo, WT, H);
  gemm_bt<<<gmG, gmB, 0, stream>>>(rbuf, WT, out, H, H, MODE_F32);
}